// Round 4
// baseline (200.218 us; speedup 1.0000x reference)
//
#include <hip/hip_runtime.h>

#define RES 128
#define FEAT 16
#define NQ 1000000
#define NBUCK_COARSE (128 * 128)        // key = (cx<<7)|cy
#define NBUCK_FINE   (128 * 128 * 8)    // key = (((cx<<7)|cy)<<3)|(cz>>4)

__device__ __forceinline__ void fma4(float4& a, float w, const float4& f) {
    a.x = fmaf(w, f.x, a.x);
    a.y = fmaf(w, f.y, a.y);
    a.z = fmaf(w, f.z, a.z);
    a.w = fmaf(w, f.w, a.w);
}

__device__ __forceinline__ int cell_coord(float v) {
    int c = (int)floorf(v * 127.0f);
    return min(max(c, 0), RES - 2);
}

template <int FINE>
__device__ __forceinline__ int bucket_key(float x, float y, float z) {
    int cx = cell_coord(x);
    int cy = cell_coord(y);
    if (FINE) {
        int cz = cell_coord(z);
        return (((cx << 7) | cy) << 3) | (cz >> 4);
    }
    return (cx << 7) | cy;
}

// ---- Pass 1: histogram of bucket keys -------------------------------------
template <int FINE>
__global__ __launch_bounds__(256) void hist_kernel(
    const float* __restrict__ xyz, unsigned int* __restrict__ hist)
{
    int q = blockIdx.x * blockDim.x + threadIdx.x;
    if (q >= NQ) return;
    float x = xyz[3 * q + 0];
    float y = xyz[3 * q + 1];
    float z = xyz[3 * q + 2];
    atomicAdd(&hist[bucket_key<FINE>(x, y, z)], 1u);
}

// ---- Pass 2: exclusive scan (single block, ITEMS per thread) --------------
template <int ITEMS>
__global__ __launch_bounds__(1024) void scan_kernel(unsigned int* __restrict__ hist)
{
    __shared__ unsigned int partial[1024];
    int t = threadIdx.x;
    unsigned int sum = 0;
    for (int i = 0; i < ITEMS; ++i) sum += hist[t * ITEMS + i];
    partial[t] = sum;
    __syncthreads();
    for (int off = 1; off < 1024; off <<= 1) {
        unsigned int v = (t >= off) ? partial[t - off] : 0u;
        __syncthreads();
        partial[t] += v;
        __syncthreads();
    }
    unsigned int excl = (t == 0) ? 0u : partial[t - 1];
    for (int i = 0; i < ITEMS; ++i) {
        unsigned int v = hist[t * ITEMS + i];
        hist[t * ITEMS + i] = excl;
        excl += v;
    }
}

// ---- Pass 3: scatter queries into bucket order ----------------------------
template <int FINE>
__global__ __launch_bounds__(256) void scatter_kernel(
    const float* __restrict__ xyz, unsigned int* __restrict__ cursor,
    float4* __restrict__ sorted)
{
    int q = blockIdx.x * blockDim.x + threadIdx.x;
    if (q >= NQ) return;
    float x = xyz[3 * q + 0];
    float y = xyz[3 * q + 1];
    float z = xyz[3 * q + 2];
    unsigned int pos = atomicAdd(&cursor[bucket_key<FINE>(x, y, z)], 1u);
    sorted[pos] = make_float4(x, y, z, __int_as_float(q));
}

// ---- Pass 4: interpolate, 4 lanes per query -------------------------------
__global__ __launch_bounds__(256) void interp_sorted4_kernel(
    const float4* __restrict__ sorted,
    const float* __restrict__ field,
    float* __restrict__ out)
{
    // bijective XCD-aware swizzle: contiguous sorted chunk per XCD L2
    int nwg = gridDim.x;
    int qn = nwg >> 3, r = nwg & 7;
    int xcd = blockIdx.x & 7, i = blockIdx.x >> 3;
    int wg = (xcd < r ? xcd * (qn + 1) : r * (qn + 1) + (xcd - r) * qn) + i;

    int t = wg * blockDim.x + threadIdx.x;
    int q = t >> 2;          // query index
    int l = t & 3;           // float4 slot within the 16-float row
    if (q >= NQ) return;

    float4 s = sorted[q];    // same addr for the 4 lanes -> broadcast
    float x = s.x, y = s.y, z = s.z;
    int oidx = __float_as_int(s.w);

    const float scale = 127.0f;
    const float h = 1.0f / 127.0f;

    int cx = cell_coord(x);
    int cy = cell_coord(y);
    int cz = cell_coord(z);

    float tx = (x - (float)cx * h) * scale;
    float ty = (y - (float)cy * h) * scale;
    float tz = (z - (float)cz * h) * scale;

    float wx0 = 1.0f - tx, wx1 = tx;
    float wy0 = 1.0f - ty, wy1 = ty;
    float wz0 = 1.0f - tz, wz1 = tz;

    float w[8] = {
        wx0 * wy0 * wz0, wx0 * wy0 * wz1,
        wx0 * wy1 * wz0, wx0 * wy1 * wz1,
        wx1 * wy0 * wz0, wx1 * wy0 * wz1,
        wx1 * wy1 * wz0, wx1 * wy1 * wz1
    };

    long long base = ((long long)cx * RES + cy) * RES + cz;
    const long long R2 = (long long)RES * RES;
    const long long offs[8] = { 0, 1, RES, RES + 1, R2, R2 + 1, R2 + RES, R2 + RES + 1 };

    float4 acc = make_float4(0.f, 0.f, 0.f, 0.f);

#pragma unroll
    for (int c = 0; c < 8; ++c) {
        const float4* p = (const float4*)(field + (base + offs[c]) * FEAT) + l;
        float4 f = *p;
        fma4(acc, w[c], f);
    }

    ((float4*)out)[(long long)oidx * 4 + l] = acc;
}

// ---- Fallback (direct kernel) ---------------------------------------------
__global__ __launch_bounds__(256) void tetra_interp_kernel(
    const float* __restrict__ xyz,
    const float* __restrict__ field,
    float* __restrict__ out)
{
    int q = blockIdx.x * blockDim.x + threadIdx.x;
    if (q >= NQ) return;

    float x = xyz[q * 3 + 0];
    float y = xyz[q * 3 + 1];
    float z = xyz[q * 3 + 2];

    const float scale = 127.0f;
    const float h = 1.0f / 127.0f;

    int cx = cell_coord(x);
    int cy = cell_coord(y);
    int cz = cell_coord(z);

    float tx = (x - (float)cx * h) * scale;
    float ty = (y - (float)cy * h) * scale;
    float tz = (z - (float)cz * h) * scale;

    float wx0 = 1.0f - tx, wx1 = tx;
    float wy0 = 1.0f - ty, wy1 = ty;
    float wz0 = 1.0f - tz, wz1 = tz;

    float w[8] = {
        wx0 * wy0 * wz0, wx0 * wy0 * wz1,
        wx0 * wy1 * wz0, wx0 * wy1 * wz1,
        wx1 * wy0 * wz0, wx1 * wy0 * wz1,
        wx1 * wy1 * wz0, wx1 * wy1 * wz1
    };

    long long base = ((long long)cx * RES + cy) * RES + cz;
    const long long R2 = (long long)RES * RES;
    const long long offs[8] = { 0, 1, RES, RES + 1, R2, R2 + 1, R2 + RES, R2 + RES + 1 };

    float4 acc0 = make_float4(0.f, 0.f, 0.f, 0.f);
    float4 acc1 = acc0, acc2 = acc0, acc3 = acc0;

#pragma unroll
    for (int c = 0; c < 8; ++c) {
        const float4* p = (const float4*)(field + (base + offs[c]) * FEAT);
        float4 f0 = p[0];
        float4 f1 = p[1];
        float4 f2 = p[2];
        float4 f3 = p[3];
        float wc = w[c];
        fma4(acc0, wc, f0);
        fma4(acc1, wc, f1);
        fma4(acc2, wc, f2);
        fma4(acc3, wc, f3);
    }

    float4* o = (float4*)(out + (long long)q * FEAT);
    o[0] = acc0;
    o[1] = acc1;
    o[2] = acc2;
    o[3] = acc3;
}

extern "C" void kernel_launch(void* const* d_in, const int* in_sizes, int n_in,
                              void* d_out, int out_size, void* d_ws, size_t ws_size,
                              hipStream_t stream) {
    const float* xyz   = (const float*)d_in[0];
    const float* field = (const float*)d_in[1];
    float* out = (float*)d_out;

    int blocks  = (NQ + 255) / 256;
    int iblocks = (NQ * 4 + 255) / 256;   // 4 lanes per query

    const size_t fine_hist_bytes   = (size_t)NBUCK_FINE * 4;     // 512 KB
    const size_t fine_needed       = fine_hist_bytes + (size_t)NQ * 16;
    const size_t coarse_needed     = 65536 + (size_t)NQ * 16;

    if (ws_size >= fine_needed) {
        unsigned int* hist = (unsigned int*)d_ws;
        float4* sorted     = (float4*)((char*)d_ws + fine_hist_bytes);

        hipMemsetAsync(d_ws, 0, fine_hist_bytes, stream);
        hist_kernel<1><<<blocks, 256, 0, stream>>>(xyz, hist);
        scan_kernel<NBUCK_FINE / 1024><<<1, 1024, 0, stream>>>(hist);
        scatter_kernel<1><<<blocks, 256, 0, stream>>>(xyz, hist, sorted);
        interp_sorted4_kernel<<<iblocks, 256, 0, stream>>>(sorted, field, out);
    } else if (ws_size >= coarse_needed) {
        unsigned int* hist = (unsigned int*)d_ws;
        float4* sorted     = (float4*)((char*)d_ws + 65536);

        hipMemsetAsync(d_ws, 0, (size_t)NBUCK_COARSE * 4, stream);
        hist_kernel<0><<<blocks, 256, 0, stream>>>(xyz, hist);
        scan_kernel<NBUCK_COARSE / 1024><<<1, 1024, 0, stream>>>(hist);
        scatter_kernel<0><<<blocks, 256, 0, stream>>>(xyz, hist, sorted);
        interp_sorted4_kernel<<<iblocks, 256, 0, stream>>>(sorted, field, out);
    } else {
        tetra_interp_kernel<<<blocks, 256, 0, stream>>>(xyz, field, out);
    }
}

// Round 6
// 144.599 us; speedup vs baseline: 1.3846x; 1.3846x over previous
//
#include <hip/hip_runtime.h>

#define RES 128
#define FEAT 16
#define NQ 1000000
#define NBUCK (128 * 128)   // bucket key = (cx<<7)|cy

typedef float v4f __attribute__((ext_vector_type(4)));

__device__ __forceinline__ void fma4(float4& a, float w, const float4& f) {
    a.x = fmaf(w, f.x, a.x);
    a.y = fmaf(w, f.y, a.y);
    a.z = fmaf(w, f.z, a.z);
    a.w = fmaf(w, f.w, a.w);
}

__device__ __forceinline__ int cell_coord(float v) {
    int c = (int)floorf(v * 127.0f);
    return min(max(c, 0), RES - 2);
}

// ---- Pass 1: histogram of bucket keys -------------------------------------
__global__ __launch_bounds__(256) void hist_kernel(
    const float* __restrict__ xyz, unsigned int* __restrict__ hist)
{
    int q = blockIdx.x * blockDim.x + threadIdx.x;
    if (q >= NQ) return;
    int cx = cell_coord(xyz[3 * q + 0]);
    int cy = cell_coord(xyz[3 * q + 1]);
    atomicAdd(&hist[(cx << 7) | cy], 1u);
}

// ---- Pass 2: exclusive scan over 16384 counters (single block) ------------
__global__ __launch_bounds__(1024) void scan_kernel(unsigned int* __restrict__ hist)
{
    __shared__ unsigned int partial[1024];
    int t = threadIdx.x;
    unsigned int vals[16];
    unsigned int sum = 0;
#pragma unroll
    for (int i = 0; i < 16; ++i) { vals[i] = hist[t * 16 + i]; sum += vals[i]; }
    partial[t] = sum;
    __syncthreads();
    for (int off = 1; off < 1024; off <<= 1) {
        unsigned int v = (t >= off) ? partial[t - off] : 0u;
        __syncthreads();
        partial[t] += v;
        __syncthreads();
    }
    unsigned int excl = (t == 0) ? 0u : partial[t - 1];
#pragma unroll
    for (int i = 0; i < 16; ++i) { unsigned int v = vals[i]; hist[t * 16 + i] = excl; excl += v; }
}

// ---- Pass 3: scatter queries into bucket order ----------------------------
__global__ __launch_bounds__(256) void scatter_kernel(
    const float* __restrict__ xyz, unsigned int* __restrict__ cursor,
    float4* __restrict__ sorted)
{
    int q = blockIdx.x * blockDim.x + threadIdx.x;
    if (q >= NQ) return;
    float x = xyz[3 * q + 0];
    float y = xyz[3 * q + 1];
    float z = xyz[3 * q + 2];
    int cx = cell_coord(x);
    int cy = cell_coord(y);
    unsigned int pos = atomicAdd(&cursor[(cx << 7) | cy], 1u);
    sorted[pos] = make_float4(x, y, z, __int_as_float(q));
}

// ---- Pass 4: interpolate, 4 lanes/query, BATCHED gathers ------------------
// All 8 corner loads are issued before any use, so each thread keeps 8
// float4 loads in flight (vmcnt depth 8) instead of ~2. This is the MLP
// fix for the latency bound seen at VGPR_Count=28.
__global__ __launch_bounds__(256) void interp_sorted4b_kernel(
    const float4* __restrict__ sorted,
    const float* __restrict__ field,
    float* __restrict__ out)
{
    // bijective XCD-aware swizzle: contiguous sorted chunk per XCD L2
    int nwg = gridDim.x;
    int qn = nwg >> 3, r = nwg & 7;
    int xcd = blockIdx.x & 7, i = blockIdx.x >> 3;
    int wg = (xcd < r ? xcd * (qn + 1) : r * (qn + 1) + (xcd - r) * qn) + i;

    int t = wg * blockDim.x + threadIdx.x;
    int q = t >> 2;          // query index
    int l = t & 3;           // float4 slot within the 16-float row
    if (q >= NQ) return;

    float4 s = sorted[q];    // same addr for 4 lanes -> broadcast
    float x = s.x, y = s.y, z = s.z;
    int oidx = __float_as_int(s.w);

    const float scale = 127.0f;
    const float h = 1.0f / 127.0f;

    int cx = cell_coord(x);
    int cy = cell_coord(y);
    int cz = cell_coord(z);

    float tx = (x - (float)cx * h) * scale;
    float ty = (y - (float)cy * h) * scale;
    float tz = (z - (float)cz * h) * scale;

    float wx0 = 1.0f - tx, wx1 = tx;
    float wy0 = 1.0f - ty, wy1 = ty;
    float wz0 = 1.0f - tz, wz1 = tz;

    float w0 = wx0 * wy0 * wz0, w1 = wx0 * wy0 * wz1;
    float w2 = wx0 * wy1 * wz0, w3 = wx0 * wy1 * wz1;
    float w4 = wx1 * wy0 * wz0, w5 = wx1 * wy0 * wz1;
    float w6 = wx1 * wy1 * wz0, w7 = wx1 * wy1 * wz1;

    int base = ((cx << 7) | cy) * RES + cz;   // cell index, < 2^21
    const char* fp = (const char*)field + ((size_t)base << 6) + ((size_t)l << 4);

    const size_t B1  = 64;                    // +1 in z   (one 16-float row)
    const size_t BY  = (size_t)RES * 64;      // +1 in y
    const size_t BX  = (size_t)RES * RES * 64;// +1 in x

    // ---- phase 1: issue all 8 gathers ----
    v4f f0 = *(const v4f*)(fp);
    v4f f1 = *(const v4f*)(fp + B1);
    v4f f2 = *(const v4f*)(fp + BY);
    v4f f3 = *(const v4f*)(fp + BY + B1);
    v4f f4 = *(const v4f*)(fp + BX);
    v4f f5 = *(const v4f*)(fp + BX + B1);
    v4f f6 = *(const v4f*)(fp + BX + BY);
    v4f f7 = *(const v4f*)(fp + BX + BY + B1);

    // ---- phase 2: weighted sum ----
    v4f acc = w0 * f0;
    acc += w1 * f1;
    acc += w2 * f2;
    acc += w3 * f3;
    acc += w4 * f4;
    acc += w5 * f5;
    acc += w6 * f6;
    acc += w7 * f7;

    __builtin_nontemporal_store(acc, (v4f*)out + ((size_t)oidx << 2) + l);
}

// ---- Fallback (direct kernel) ---------------------------------------------
__global__ __launch_bounds__(256) void tetra_interp_kernel(
    const float* __restrict__ xyz,
    const float* __restrict__ field,
    float* __restrict__ out)
{
    int q = blockIdx.x * blockDim.x + threadIdx.x;
    if (q >= NQ) return;

    float x = xyz[q * 3 + 0];
    float y = xyz[q * 3 + 1];
    float z = xyz[q * 3 + 2];

    const float scale = 127.0f;
    const float h = 1.0f / 127.0f;

    int cx = cell_coord(x);
    int cy = cell_coord(y);
    int cz = cell_coord(z);

    float tx = (x - (float)cx * h) * scale;
    float ty = (y - (float)cy * h) * scale;
    float tz = (z - (float)cz * h) * scale;

    float wx0 = 1.0f - tx, wx1 = tx;
    float wy0 = 1.0f - ty, wy1 = ty;
    float wz0 = 1.0f - tz, wz1 = tz;

    float w[8] = {
        wx0 * wy0 * wz0, wx0 * wy0 * wz1,
        wx0 * wy1 * wz0, wx0 * wy1 * wz1,
        wx1 * wy0 * wz0, wx1 * wy0 * wz1,
        wx1 * wy1 * wz0, wx1 * wy1 * wz1
    };

    long long base = ((long long)cx * RES + cy) * RES + cz;
    const long long R2 = (long long)RES * RES;
    const long long offs[8] = { 0, 1, RES, RES + 1, R2, R2 + 1, R2 + RES, R2 + RES + 1 };

    float4 acc0 = make_float4(0.f, 0.f, 0.f, 0.f);
    float4 acc1 = acc0, acc2 = acc0, acc3 = acc0;

#pragma unroll
    for (int c = 0; c < 8; ++c) {
        const float4* p = (const float4*)(field + (base + offs[c]) * FEAT);
        float4 f0 = p[0];
        float4 f1 = p[1];
        float4 f2 = p[2];
        float4 f3 = p[3];
        float wc = w[c];
        fma4(acc0, wc, f0);
        fma4(acc1, wc, f1);
        fma4(acc2, wc, f2);
        fma4(acc3, wc, f3);
    }

    float4* o = (float4*)(out + (long long)q * FEAT);
    o[0] = acc0;
    o[1] = acc1;
    o[2] = acc2;
    o[3] = acc3;
}

extern "C" void kernel_launch(void* const* d_in, const int* in_sizes, int n_in,
                              void* d_out, int out_size, void* d_ws, size_t ws_size,
                              hipStream_t stream) {
    const float* xyz   = (const float*)d_in[0];
    const float* field = (const float*)d_in[1];
    float* out = (float*)d_out;

    int blocks  = (NQ + 255) / 256;
    int iblocks = (NQ * 4 + 255) / 256;   // 4 lanes per query

    const size_t sorted_off = 65536;
    const size_t needed     = sorted_off + (size_t)NQ * 16;

    if (ws_size < needed) {
        tetra_interp_kernel<<<blocks, 256, 0, stream>>>(xyz, field, out);
        return;
    }

    unsigned int* hist  = (unsigned int*)d_ws;
    float4* sorted      = (float4*)((char*)d_ws + sorted_off);

    (void)hipMemsetAsync(d_ws, 0, (size_t)NBUCK * 4, stream);
    hist_kernel<<<blocks, 256, 0, stream>>>(xyz, hist);
    scan_kernel<<<1, 1024, 0, stream>>>(hist);
    scatter_kernel<<<blocks, 256, 0, stream>>>(xyz, hist, sorted);
    interp_sorted4b_kernel<<<iblocks, 256, 0, stream>>>(sorted, field, out);
}